// Round 1
// baseline (335.778 us; speedup 1.0000x reference)
//
#include <hip/hip_runtime.h>
#include <math.h>

typedef unsigned short u16;
typedef unsigned int u32;
typedef __bf16 bf16x8_t __attribute__((ext_vector_type(8)));
typedef float f32x4_t __attribute__((ext_vector_type(4)));

__device__ __forceinline__ u16 f2bf(float f) {
  __bf16 b = (__bf16)f;
  return __builtin_bit_cast(u16, b);
}

__device__ __forceinline__ void gld16(const void* g, void* l) {
  __builtin_amdgcn_global_load_lds(
      (const __attribute__((address_space(1))) void*)g,
      (__attribute__((address_space(3))) void*)l, 16, 0, 0);
}

// ---------------------------------------------------------------------------
// cast fp32 -> bf16 (weights)
__global__ __launch_bounds__(256) void cast_kernel(const float* __restrict__ src,
                                                   u16* __restrict__ dst, int n) {
  int i = (blockIdx.x * 256 + threadIdx.x) * 4;
  if (i < n) {
    float4 v = *(const float4*)(src + i);
    uint2 o;
    o.x = (u32)f2bf(v.x) | ((u32)f2bf(v.y) << 16);
    o.y = (u32)f2bf(v.z) | ((u32)f2bf(v.w) << 16);
    *(uint2*)(dst + i) = o;
  }
}

// ---------------------------------------------------------------------------
// b2ob[c] = b2[c] + sum_i grn_b[i]*w2[c][i]
__global__ __launch_bounds__(64) void b2ob_kernel(const float* __restrict__ w2,
                                                  const float* __restrict__ grn_b,
                                                  const float* __restrict__ b2,
                                                  float* __restrict__ out) {
  int c = blockIdx.x;
  int l = threadIdx.x;
  float p = 0.f;
  for (int i = l; i < 1536; i += 64) p += grn_b[i] * w2[(size_t)c * 1536 + i];
  #pragma unroll
  for (int s = 32; s; s >>= 1) p += __shfl_xor(p, s);
  if (l == 0) out[c] = b2[c] + p;
}

// ---------------------------------------------------------------------------
// depthwise conv (K=7, pad 3) + LayerNorm over C, output bf16 [B*T][512]
__global__ __launch_bounds__(256) void conv_ln_kernel(const float* __restrict__ X,
                                                      const float* __restrict__ Wd,
                                                      const float* __restrict__ bd,
                                                      const float* __restrict__ lng,
                                                      const float* __restrict__ lnb,
                                                      u16* __restrict__ Y) {
  __shared__ float red0[256];
  __shared__ float red1[256];
  __shared__ float mu_s[16], rs_s[16];
  __shared__ __align__(16) u16 stage[16 * 520];

  const int tid = threadIdx.x;
  const int tl = tid & 15;        // local t
  const int cg = tid >> 4;        // channel group (32 c each)
  const int b = blockIdx.y;
  const int t0 = blockIdx.x * 16;
  const int t = t0 + tl;

  const float* xb = X + (size_t)b * 512 * 2048;
  float yv[32];
  float sum = 0.f, sq = 0.f;
  #pragma unroll
  for (int j = 0; j < 32; ++j) {
    int c = cg * 32 + j;
    const float* xr = xb + (size_t)c * 2048;
    const float* wr = Wd + c * 7;
    float a = bd[c];
    #pragma unroll
    for (int k = 0; k < 7; ++k) {
      int tt = t + k - 3;
      if (tt >= 0 && tt < 2048) a += xr[tt] * wr[k];
    }
    yv[j] = a;
    sum += a;
    sq += a * a;
  }
  red0[tid] = sum;
  red1[tid] = sq;
  __syncthreads();
  if (tid < 16) {
    float s = 0.f, q = 0.f;
    #pragma unroll
    for (int g = 0; g < 16; ++g) { s += red0[g * 16 + tid]; q += red1[g * 16 + tid]; }
    float mu = s * (1.f / 512.f);
    float var = q * (1.f / 512.f) - mu * mu;
    mu_s[tid] = mu;
    rs_s[tid] = rsqrtf(var + 1e-6f);
  }
  __syncthreads();
  float mu = mu_s[tl], rs = rs_s[tl];
  #pragma unroll
  for (int j = 0; j < 32; ++j) {
    int c = cg * 32 + j;
    float v = (yv[j] - mu) * rs * lng[c] + lnb[c];
    stage[tl * 520 + c] = f2bf(v);
  }
  __syncthreads();
  // coalesced write: 16 rows x 512 bf16
  #pragma unroll
  for (int it = 0; it < 4; ++it) {
    int idx = it * 256 + tid;   // 0..1023
    int row = idx >> 6;         // 0..15
    int cb = idx & 63;          // 0..63 (8 bf16 chunks)
    uint4 v = *(const uint4*)(stage + row * 520 + cb * 8);
    *(uint4*)(Y + (size_t)(b * 2048 + t0 + row) * 512 + cb * 8) = v;
  }
}

// ---------------------------------------------------------------------------
// GEMM1: h[m][n] = gelu( y_ln[m][:] . w1[n][:] + b1[n] ), M=32768 K=512 N=1536
// also accumulates gsum[b][n] += sum_rows gelu^2 (for GRN)
__global__ __launch_bounds__(256, 2) void gemm1_kernel(const u16* __restrict__ A,
                                                       const u16* __restrict__ B,
                                                       const float* __restrict__ b1,
                                                       u16* __restrict__ H,
                                                       float* __restrict__ gsum) {
  __shared__ __align__(16) u16 smem[128 * 136];   // tiles: 2x 128*64; epilogue stage 128x136
  u16* lA = smem;
  u16* lB = smem + 128 * 64;

  const int tid = threadIdx.x;
  const int w = tid >> 6;
  const int l = tid & 63;
  const int m0 = blockIdx.x * 128;
  const int n0 = blockIdx.y * 128;
  const int bidx = m0 >> 11;
  const int wm = w >> 1, wn = w & 1;

  f32x4_t acc[4][4];
  #pragma unroll
  for (int i = 0; i < 4; ++i)
    #pragma unroll
    for (int j = 0; j < 4; ++j) {
      f32x4_t z = {0.f, 0.f, 0.f, 0.f};
      acc[i][j] = z;
    }

  const int rowInc = w * 8 + (l >> 3);
  const int colE = (l & 7) * 8;
  const u16* Abase = A + (size_t)(m0 + rowInc) * 512 + colE;
  const u16* Bbase = B + (size_t)(n0 + rowInc) * 512 + colE;
  const int ldsOff = w * 512;   // elems; + c*2048; HW adds lane*16B

  for (int kt = 0; kt < 512; kt += 64) {
    #pragma unroll
    for (int c = 0; c < 4; ++c) {
      gld16(Abase + (size_t)(c * 32) * 512 + kt, lA + c * 2048 + ldsOff);
      gld16(Bbase + (size_t)(c * 32) * 512 + kt, lB + c * 2048 + ldsOff);
    }
    __syncthreads();
    #pragma unroll
    for (int kk = 0; kk < 2; ++kk) {
      bf16x8_t af[4], bfr[4];
      #pragma unroll
      for (int f = 0; f < 4; ++f) {
        int arow = wm * 64 + f * 16 + (l & 15);
        af[f] = *(const bf16x8_t*)(lA + arow * 64 + kk * 32 + (l >> 4) * 8);
        int brow = wn * 64 + f * 16 + (l & 15);
        bfr[f] = *(const bf16x8_t*)(lB + brow * 64 + kk * 32 + (l >> 4) * 8);
      }
      #pragma unroll
      for (int i = 0; i < 4; ++i)
        #pragma unroll
        for (int j = 0; j < 4; ++j)
          acc[i][j] = __builtin_amdgcn_mfma_f32_16x16x32_bf16(af[i], bfr[j], acc[i][j], 0, 0, 0);
    }
    __syncthreads();
  }

  // epilogue: bias + exact GELU, stage bf16 to LDS, atomic sumsq per column
  const int lrow = (l >> 4) * 4;
  const int lcol = l & 15;
  float bj[4];
  #pragma unroll
  for (int j = 0; j < 4; ++j) bj[j] = b1[n0 + wn * 64 + j * 16 + lcol];

  float ss[4] = {0.f, 0.f, 0.f, 0.f};
  #pragma unroll
  for (int i = 0; i < 4; ++i) {
    int row = wm * 64 + i * 16 + lrow;
    #pragma unroll
    for (int j = 0; j < 4; ++j) {
      int col = wn * 64 + j * 16 + lcol;
      #pragma unroll
      for (int r = 0; r < 4; ++r) {
        float v = acc[i][j][r] + bj[j];
        float g = 0.5f * v * (1.0f + erff(v * 0.70710678118654752f));
        ss[j] += g * g;
        smem[(row + r) * 136 + col] = f2bf(g);
      }
    }
  }
  #pragma unroll
  for (int j = 0; j < 4; ++j) {
    float v = ss[j];
    v += __shfl_xor(v, 16);
    v += __shfl_xor(v, 32);
    if ((l >> 4) == 0)
      atomicAdd(&gsum[bidx * 1536 + n0 + wn * 64 + j * 16 + lcol], v);
  }
  __syncthreads();
  #pragma unroll
  for (int it = 0; it < 8; ++it) {
    int idx = it * 256 + tid;   // 0..2047
    int row = idx >> 4;         // 0..127
    int cb = idx & 15;
    uint4 v = *(const uint4*)(smem + row * 136 + cb * 8);
    *(uint4*)(H + (size_t)(m0 + row) * 1536 + n0 + cb * 8) = v;
  }
}

// ---------------------------------------------------------------------------
// GRN scale: s[b][i] = 1 + grn_g[i] * gx / (mean_i(gx) + 1e-6), gx = sqrt(gsum)
__global__ __launch_bounds__(256) void grn_kernel(const float* __restrict__ gsum,
                                                  const float* __restrict__ grn_g,
                                                  float* __restrict__ svec) {
  __shared__ float red[256];
  int b = blockIdx.x, tid = threadIdx.x;
  float gx[6];
  float part = 0.f;
  #pragma unroll
  for (int it = 0; it < 6; ++it) {
    int i = it * 256 + tid;
    gx[it] = sqrtf(gsum[b * 1536 + i]);
    part += gx[it];
  }
  red[tid] = part;
  __syncthreads();
  for (int s = 128; s; s >>= 1) {
    if (tid < s) red[tid] += red[tid + s];
    __syncthreads();
  }
  float inv = 1.0f / (red[0] * (1.f / 1536.f) + 1e-6f);
  #pragma unroll
  for (int it = 0; it < 6; ++it) {
    int i = it * 256 + tid;
    svec[b * 1536 + i] = 1.0f + grn_g[i] * gx[it] * inv;
  }
}

// ---------------------------------------------------------------------------
// GEMM2: out[b][c][t] = x[b][c][t] + (h[m][:] * s[b][:]) . w2[c][:] + b2ob[c]
// M=32768 K=1536 N=512.  A reg-staged (scale applied), B via global_load_lds.
__global__ __launch_bounds__(256, 2) void gemm2_kernel(const u16* __restrict__ Hs,
                                                       const u16* __restrict__ B,
                                                       const float* __restrict__ svec,
                                                       const float* __restrict__ b2ob,
                                                       const float* __restrict__ X,
                                                       float* __restrict__ Out) {
  __shared__ __align__(16) u16 smem[16512];  // tiles 2x8192 u16 (32KB); ostage 64x129 f32 (33024B)
  u16* lA = smem;
  u16* lB = smem + 8192;

  const int tid = threadIdx.x;
  const int w = tid >> 6;
  const int l = tid & 63;
  const int m0 = blockIdx.x * 128;
  const int n0 = blockIdx.y * 128;
  const int bidx = m0 >> 11;
  const int t0 = m0 & 2047;
  const int wm = w >> 1, wn = w & 1;

  f32x4_t acc[4][4];
  #pragma unroll
  for (int i = 0; i < 4; ++i)
    #pragma unroll
    for (int j = 0; j < 4; ++j) {
      f32x4_t z = {0.f, 0.f, 0.f, 0.f};
      acc[i][j] = z;
    }

  const int rowInc = w * 8 + (l >> 3);
  const int colE = (l & 7) * 8;
  const u16* Abase = Hs + (size_t)(m0 + rowInc) * 1536 + colE;
  const u16* Bbase = B + (size_t)(n0 + rowInc) * 1536 + colE;
  const float* sb = svec + bidx * 1536 + colE;
  const int ldsOff = w * 512;

  for (int kt = 0; kt < 1536; kt += 64) {
    // B tile: async direct-to-LDS
    #pragma unroll
    for (int c = 0; c < 4; ++c)
      gld16(Bbase + (size_t)(c * 32) * 1536 + kt, lB + c * 2048 + ldsOff);
    // A tile: reg-staged with GRN scale folded in
    float4 s0 = *(const float4*)(sb + kt);
    float4 s1 = *(const float4*)(sb + kt + 4);
    float sv[8] = {s0.x, s0.y, s0.z, s0.w, s1.x, s1.y, s1.z, s1.w};
    #pragma unroll
    for (int c = 0; c < 4; ++c) {
      bf16x8_t hv = *(const bf16x8_t*)(Abase + (size_t)(c * 32) * 1536 + kt);
      bf16x8_t ov;
      #pragma unroll
      for (int e = 0; e < 8; ++e) ov[e] = (__bf16)((float)hv[e] * sv[e]);
      *(bf16x8_t*)(lA + c * 2048 + ldsOff + l * 8) = ov;
    }
    __syncthreads();
    #pragma unroll
    for (int kk = 0; kk < 2; ++kk) {
      bf16x8_t af[4], bfr[4];
      #pragma unroll
      for (int f = 0; f < 4; ++f) {
        int arow = wm * 64 + f * 16 + (l & 15);
        af[f] = *(const bf16x8_t*)(lA + arow * 64 + kk * 32 + (l >> 4) * 8);
        int brow = wn * 64 + f * 16 + (l & 15);
        bfr[f] = *(const bf16x8_t*)(lB + brow * 64 + kk * 32 + (l >> 4) * 8);
      }
      #pragma unroll
      for (int i = 0; i < 4; ++i)
        #pragma unroll
        for (int j = 0; j < 4; ++j)
          acc[i][j] = __builtin_amdgcn_mfma_f32_16x16x32_bf16(af[i], bfr[j], acc[i][j], 0, 0, 0);
    }
    __syncthreads();
  }

  // epilogue: transpose through LDS (fp32, stride 129 -> conflict-free col read),
  // add b2ob + residual, write out[b][c][t]
  float* ostage = (float*)smem;
  #pragma unroll
  for (int half = 0; half < 2; ++half) {
    if (wm == half) {
      #pragma unroll
      for (int i = 0; i < 4; ++i) {
        int lr = i * 16 + (l >> 4) * 4;   // 0..63 within half
        #pragma unroll
        for (int j = 0; j < 4; ++j) {
          int col = wn * 64 + j * 16 + (l & 15);
          #pragma unroll
          for (int r = 0; r < 4; ++r) ostage[(lr + r) * 129 + col] = acc[i][j][r];
        }
      }
    }
    __syncthreads();
    #pragma unroll
    for (int it = 0; it < 32; ++it) {
      int cl = it * 4 + w;      // 0..127
      int c = n0 + cl;
      float v = ostage[l * 129 + cl];
      size_t oidx = ((size_t)bidx * 512 + c) * 2048 + t0 + half * 64 + l;
      Out[oidx] = v + b2ob[c] + X[oidx];
    }
    __syncthreads();
  }
}

// ---------------------------------------------------------------------------
extern "C" void kernel_launch(void* const* d_in, const int* in_sizes, int n_in,
                              void* d_out, int out_size, void* d_ws, size_t ws_size,
                              hipStream_t stream) {
  const float* x     = (const float*)d_in[0];
  const float* dw_w  = (const float*)d_in[1];
  const float* dw_b  = (const float*)d_in[2];
  const float* ln_g  = (const float*)d_in[3];
  const float* ln_b  = (const float*)d_in[4];
  const float* w1    = (const float*)d_in[5];
  const float* b1    = (const float*)d_in[6];
  const float* grn_g = (const float*)d_in[7];
  const float* grn_b = (const float*)d_in[8];
  const float* w2    = (const float*)d_in[9];
  const float* b2    = (const float*)d_in[10];
  float* out = (float*)d_out;

  // workspace layout (all 16B aligned)
  u16* y_ln = (u16*)d_ws;                             // 32768*512
  u16* h    = y_ln + (size_t)32768 * 512;             // 32768*1536
  u16* w1b  = h + (size_t)32768 * 1536;               // 1536*512
  u16* w2b  = w1b + (size_t)1536 * 512;               // 512*1536
  float* gsum = (float*)(w2b + (size_t)512 * 1536);   // 16*1536
  float* svec = gsum + 16 * 1536;                     // 16*1536
  float* b2ob = svec + 16 * 1536;                     // 512

  hipMemsetAsync(gsum, 0, 16 * 1536 * sizeof(float), stream);
  cast_kernel<<<768, 256, 0, stream>>>(w1, w1b, 1536 * 512);
  cast_kernel<<<768, 256, 0, stream>>>(w2, w2b, 512 * 1536);
  b2ob_kernel<<<512, 64, 0, stream>>>(w2, grn_b, b2, b2ob);
  conv_ln_kernel<<<dim3(128, 16), 256, 0, stream>>>(x, dw_w, dw_b, ln_g, ln_b, y_ln);
  gemm1_kernel<<<dim3(256, 12), 256, 0, stream>>>(y_ln, w1b, b1, h, gsum);
  grn_kernel<<<16, 256, 0, stream>>>(gsum, grn_g, svec);
  gemm2_kernel<<<dim3(256, 4), 256, 0, stream>>>(h, w2b, svec, b2ob, x, out);
}